// Round 12
// baseline (304.526 us; speedup 1.0000x reference)
//
#include <hip/hip_runtime.h>
#include <stdint.h>

#define TTOK 1024
#define DMODEL 1024
#define NEXP 16
#define TOPK 4
#define INTER 512
#define NSHI 1024
#define RSCALE 2.5f

typedef __bf16 bf16;
typedef __bf16 bf16x8 __attribute__((ext_vector_type(8)));
typedef __bf16 bf16x4 __attribute__((ext_vector_type(4)));
typedef float f32x4 __attribute__((ext_vector_type(4)));

// bf16 weight buffer layout (element offsets) — ALL weights converted (round-9 scheme)
#define OFF_GP 0L
#define OFF_UP 8388608L   // 16*512*1024
#define OFF_DP 16777216L
#define OFF_SG 25165824L
#define OFF_SU 26214400L
#define OFF_SD 27262976L
#define WTOT   28311552L  // total bf16 elems

#define SCORES_BLOCKS 256
#define CONV_BLOCKS 27648  // WTOT/4 float4 units / 256

// ---------------- prep: scores (+x->bf16) CONCURRENT with weight fp32->bf16 ----------------
// (round-9 proven: 45 us, convert hides under nothing but IS the long pole; scores ~12)
__global__ __launch_bounds__(256)
void prep_kernel(const float* __restrict__ x, const float* __restrict__ gw,
                 float* __restrict__ scores, bf16* __restrict__ xbf,
                 const float* __restrict__ s0, const float* __restrict__ s1,
                 const float* __restrict__ s2, const float* __restrict__ s3,
                 const float* __restrict__ s4, const float* __restrict__ s5,
                 bf16* __restrict__ dst) {
  __shared__ float red[256];
  const int b = blockIdx.x;
  const int tid = threadIdx.x;
  if (b < SCORES_BLOCKS) {
    const long xb = (long)b * 1024;
#pragma unroll
    for (int p = 0; p < 4; ++p) {
      const long j = xb + p * 256 + tid;
      const float4 v = ((const float4*)x)[j];
      bf16x4 o;
      o.x = (bf16)v.x; o.y = (bf16)v.y; o.z = (bf16)v.z; o.w = (bf16)v.w;
      ((bf16x4*)xbf)[j] = o;
    }
    const int kq = tid >> 6;
    const int lane = tid & 63;
    const int tl = lane >> 4;
    const int e = lane & 15;
    const long token = (long)b * 4 + tl;
    float acc = 0.f;
    const int dbase = kq * 256;
#pragma unroll 8
    for (int i = 0; i < 256; i += 4) {
      const int d = dbase + i;
      const float4 xv = *(const float4*)&x[token * DMODEL + d];
      const float4 wv = *(const float4*)&gw[e * DMODEL + d];
      acc += xv.x * wv.x + xv.y * wv.y + xv.z * wv.z + xv.w * wv.w;
    }
    red[tid] = acc;
    __syncthreads();
    if (kq == 0) {
      const float s = red[lane] + red[64 + lane] + red[128 + lane] + red[192 + lane];
      scores[token * 16 + e] = s;
    }
  } else {
    const long i = (long)(b - SCORES_BLOCKS) * 256 + tid;  // float4 index
    const float* src;
    long local;
    if (i < 2097152)      { src = s0; local = i; }
    else if (i < 4194304) { src = s1; local = i - 2097152; }
    else if (i < 6291456) { src = s2; local = i - 4194304; }
    else if (i < 6553600) { src = s3; local = i - 6291456; }
    else if (i < 6815744) { src = s4; local = i - 6553600; }
    else                  { src = s5; local = i - 6815744; }
    const float4 v = ((const float4*)src)[local];
    bf16x4 o;
    o.x = (bf16)v.x; o.y = (bf16)v.y; o.z = (bf16)v.z; o.w = (bf16)v.w;
    ((bf16x4*)dst)[i] = o;
  }
}

// ---------------- route: top-k + plan + fill, fused single-block (round-9 proven) --------
__global__ __launch_bounds__(1024)
void route_kernel(const float* __restrict__ scores, const float* __restrict__ gb,
                  float* __restrict__ tokW, int* __restrict__ slotTok,
                  int* __restrict__ tokSlot, int* __restrict__ offs,
                  int* __restrict__ tileE, int* __restrict__ tileR,
                  int* __restrict__ tileCnt) {
  __shared__ int cnt[NEXP], cur[NEXP];
  const int t = threadIdx.x;
  if (t < NEXP) cnt[t] = 0;
  __syncthreads();
  float sc[NEXP], s[NEXP];
#pragma unroll
  for (int e = 0; e < NEXP; ++e) {
    const float l = scores[t * NEXP + e];
    sc[e] = 1.f / (1.f + expf(-l));
    s[e] = sc[e] + gb[e];
  }
  float gsc[4];
#pragma unroll
  for (int g = 0; g < 4; ++g) {
    const float a = s[4 * g], b = s[4 * g + 1], c = s[4 * g + 2], d = s[4 * g + 3];
    gsc[g] = fmaxf(fmaxf(fmaxf(a + b, a + c), fmaxf(a + d, b + c)),
                   fmaxf(b + d, c + d));
  }
  int g0 = 0;
  for (int g = 1; g < 4; ++g) if (gsc[g] > gsc[g0]) g0 = g;
  int g1 = (g0 == 0) ? 1 : 0;
  for (int g = 0; g < 4; ++g) if (g != g0 && gsc[g] > gsc[g1]) g1 = g;
  float m[NEXP];
#pragma unroll
  for (int e = 0; e < NEXP; ++e) {
    const int g = e >> 2;
    m[e] = (g == g0 || g == g1) ? s[e] : -1.f;
  }
  int idx[TOPK]; float wv[TOPK]; float wsum = 0.f;
  for (int k = 0; k < TOPK; ++k) {
    int am = 0; float best = m[0];
    for (int e2 = 1; e2 < NEXP; ++e2)
      if (m[e2] > best) { best = m[e2]; am = e2; }
    idx[k] = am; wv[k] = sc[am]; wsum += sc[am]; m[am] = -2.f;
  }
#pragma unroll
  for (int k = 0; k < TOPK; ++k) atomicAdd(&cnt[idx[k]], 1);
  __syncthreads();
  if (t == 0) {
    int acc = 0;
#pragma unroll
    for (int e = 0; e < NEXP; ++e) {
      offs[e] = acc; cur[e] = acc; acc += cnt[e];
    }
    offs[NEXP] = acc;
    int tc = 0;
    int roff = 0;
    for (int e = 0; e < NEXP; ++e) {
      const int end = roff + cnt[e];
      for (int r = roff; r < end; r += 128) { tileE[tc] = e; tileR[tc] = r; ++tc; }
      roff = end;
    }
    for (int r = 0; r < TTOK; r += 128) { tileE[tc] = NEXP; tileR[tc] = r; ++tc; }
    tileCnt[0] = tc;  // <= 47 + 8 = 55
  }
  __syncthreads();
  const float scl = RSCALE / wsum;
#pragma unroll
  for (int k = 0; k < TOPK; ++k) {
    const int slot = atomicAdd(&cur[idx[k]], 1);
    slotTok[slot] = t;
    tokSlot[t * TOPK + k] = slot;
    tokW[t * TOPK + k] = wv[k] * scl;
  }
}

// ---------------- gate+up grouped GEMM: BARRIER-FREE, LDS-FREE, direct fragments ---------
// Each lane loads its MFMA fragments straight from L2/L3-resident bf16 buffers
// (per-lane bf16x8 at row*LD + k + q*8 == the fragment layout). Manual depth-2
// register prefetch, zero barriers in the k-loop: no drain points, waves slip.
__global__ __launch_bounds__(256, 2)
void gateup_gemm(const bf16* __restrict__ xbf, const int* __restrict__ slotTok,
                 const int* __restrict__ offs, const int* __restrict__ tileE,
                 const int* __restrict__ tileR, const int* __restrict__ tileCnt,
                 const bf16* __restrict__ wbf,
                 bf16* __restrict__ interR, bf16* __restrict__ interS) {
  const int y = blockIdx.y;
  if (y >= tileCnt[0]) return;
  const int e = tileE[y];
  const bool shd = (e == NEXP);
  const int n0 = blockIdx.x * 64;
  if (!shd && n0 >= INTER) return;
  const int rowStart = tileR[y];
  const int rowEnd = shd ? rowStart + 128 : offs[e + 1];
  const bf16* wgp = shd ? wbf + OFF_SG : wbf + OFF_GP + (long)e * INTER * DMODEL;
  const bf16* wup = shd ? wbf + OFF_SU : wbf + OFF_UP + (long)e * INTER * DMODEL;

  const int tid = threadIdx.x;
  const int lane = tid & 63;
  const int wv = tid >> 6;
  const int q = lane >> 4;
  const int l15 = lane & 15;
  const int wm = (wv >> 1) * 64;
  const int wn = (wv & 1) * 32;

  // per-lane A fragment base pointers (token gather once, in registers)
  const bf16* aP[4];
#pragma unroll
  for (int mi = 0; mi < 4; ++mi) {
    const int r = rowStart + wm + 16 * mi + l15;
    const int tok = shd ? r : slotTok[r < rowEnd ? r : rowStart];
    aP[mi] = xbf + (long)tok * DMODEL + q * 8;
  }
  // per-lane B fragment base pointers
  const bf16* gP[2]; const bf16* uP[2];
#pragma unroll
  for (int ni = 0; ni < 2; ++ni) {
    const long nrow = n0 + wn + 16 * ni + l15;
    gP[ni] = wgp + nrow * DMODEL + q * 8;
    uP[ni] = wup + nrow * DMODEL + q * 8;
  }

  const f32x4 fz = {0.f, 0.f, 0.f, 0.f};
  f32x4 accG[4][2], accU[4][2];
#pragma unroll
  for (int i = 0; i < 4; ++i)
#pragma unroll
    for (int j = 0; j < 2; ++j) { accG[i][j] = fz; accU[i][j] = fz; }

  // two named fragment sets: set A = k, set B = k+32; depth-2, no barriers
  bf16x8 aFA[4], gFA[2], uFA[2], aFB[4], gFB[2], uFB[2];
#pragma unroll
  for (int mi = 0; mi < 4; ++mi) aFA[mi] = *(const bf16x8*)(aP[mi]);
#pragma unroll
  for (int ni = 0; ni < 2; ++ni) {
    gFA[ni] = *(const bf16x8*)(gP[ni]);
    uFA[ni] = *(const bf16x8*)(uP[ni]);
  }
#pragma unroll
  for (int mi = 0; mi < 4; ++mi) aFB[mi] = *(const bf16x8*)(aP[mi] + 32);
#pragma unroll
  for (int ni = 0; ni < 2; ++ni) {
    gFB[ni] = *(const bf16x8*)(gP[ni] + 32);
    uFB[ni] = *(const bf16x8*)(uP[ni] + 32);
  }

  for (int k = 0; k < DMODEL; k += 64) {
    // compute set A (k); prefetch k+64 into set A
    {
      const int kp = k + 64;
      bf16x8 aT[4], gT[2], uT[2];
      if (kp < DMODEL) {
#pragma unroll
        for (int mi = 0; mi < 4; ++mi) aT[mi] = *(const bf16x8*)(aP[mi] + kp);
#pragma unroll
        for (int ni = 0; ni < 2; ++ni) {
          gT[ni] = *(const bf16x8*)(gP[ni] + kp);
          uT[ni] = *(const bf16x8*)(uP[ni] + kp);
        }
      }
#pragma unroll
      for (int ni = 0; ni < 2; ++ni)
#pragma unroll
        for (int mi = 0; mi < 4; ++mi) {
          accG[mi][ni] = __builtin_amdgcn_mfma_f32_16x16x32_bf16(aFA[mi], gFA[ni], accG[mi][ni], 0, 0, 0);
          accU[mi][ni] = __builtin_amdgcn_mfma_f32_16x16x32_bf16(aFA[mi], uFA[ni], accU[mi][ni], 0, 0, 0);
        }
      if (kp < DMODEL) {
#pragma unroll
        for (int mi = 0; mi < 4; ++mi) aFA[mi] = aT[mi];
#pragma unroll
        for (int ni = 0; ni < 2; ++ni) { gFA[ni] = gT[ni]; uFA[ni] = uT[ni]; }
      }
    }
    // compute set B (k+32); prefetch k+96 into set B
    {
      const int kp = k + 96;
      bf16x8 aT[4], gT[2], uT[2];
      if (kp < DMODEL) {
#pragma unroll
        for (int mi = 0; mi < 4; ++mi) aT[mi] = *(const bf16x8*)(aP[mi] + kp);
#pragma unroll
        for (int ni = 0; ni < 2; ++ni) {
          gT[ni] = *(const bf16x8*)(gP[ni] + kp);
          uT[ni] = *(const bf16x8*)(uP[ni] + kp);
        }
      }
#pragma unroll
      for (int ni = 0; ni < 2; ++ni)
#pragma unroll
        for (int mi = 0; mi < 4; ++mi) {
          accG[mi][ni] = __builtin_amdgcn_mfma_f32_16x16x32_bf16(aFB[mi], gFB[ni], accG[mi][ni], 0, 0, 0);
          accU[mi][ni] = __builtin_amdgcn_mfma_f32_16x16x32_bf16(aFB[mi], uFB[ni], accU[mi][ni], 0, 0, 0);
        }
      if (kp < DMODEL) {
#pragma unroll
        for (int mi = 0; mi < 4; ++mi) aFB[mi] = aT[mi];
#pragma unroll
        for (int ni = 0; ni < 2; ++ni) { gFB[ni] = gT[ni]; uFB[ni] = uT[ni]; }
      }
    }
  }

  bf16* outI = shd ? interS : interR;
  const int ldI = shd ? NSHI : INTER;
#pragma unroll
  for (int mi = 0; mi < 4; ++mi)
#pragma unroll
    for (int r = 0; r < 4; ++r) {
      const int rowLoc = wm + 16 * mi + q * 4 + r;
      const int row = rowStart + rowLoc;
      if (row < rowEnd) {
#pragma unroll
        for (int ni = 0; ni < 2; ++ni) {
          const float gg = accG[mi][ni][r];
          const float uu = accU[mi][ni][r];
          const float sv = gg / (1.f + __expf(-gg)) * uu;
          outI[(long)row * ldI + (n0 + wn + 16 * ni + l15)] = (bf16)sv;
        }
      }
    }
}

// ---------------- down grouped GEMM: BARRIER-FREE, LDS-FREE -> per-slot fp32 rows --------
__global__ __launch_bounds__(256, 2)
void down_gemm(const bf16* __restrict__ interR, const bf16* __restrict__ interS,
               const int* __restrict__ offs, const int* __restrict__ tileE,
               const int* __restrict__ tileR, const int* __restrict__ tileCnt,
               const bf16* __restrict__ wbf,
               float* __restrict__ dsR, float* __restrict__ dsS) {
  const int y = blockIdx.y;
  if (y >= tileCnt[0]) return;
  const int e = tileE[y];
  const bool shd = (e == NEXP);
  const int n0 = blockIdx.x * 64;
  const int rowStart = tileR[y];
  const int rowEnd = shd ? rowStart + 128 : offs[e + 1];
  const int Kd = shd ? NSHI : INTER;
  const bf16* A = shd ? interS : interR;
  const bf16* wd = shd ? wbf + OFF_SD : wbf + OFF_DP + (long)e * DMODEL * INTER;

  const int tid = threadIdx.x;
  const int lane = tid & 63;
  const int wv = tid >> 6;
  const int q = lane >> 4;
  const int l15 = lane & 15;
  const int wm = (wv >> 1) * 64;
  const int wn = (wv & 1) * 32;

  const bf16* aP[4];
#pragma unroll
  for (int mi = 0; mi < 4; ++mi)
    aP[mi] = A + (long)(rowStart + wm + 16 * mi + l15) * Kd + q * 8;
  const bf16* bP[2];
#pragma unroll
  for (int ni = 0; ni < 2; ++ni)
    bP[ni] = wd + (long)(n0 + wn + 16 * ni + l15) * Kd + q * 8;

  const f32x4 fz = {0.f, 0.f, 0.f, 0.f};
  f32x4 acc[4][2];
#pragma unroll
  for (int i = 0; i < 4; ++i)
#pragma unroll
    for (int j = 0; j < 2; ++j) acc[i][j] = fz;

  bf16x8 aFA[4], bFA[2], aFB[4], bFB[2];
#pragma unroll
  for (int mi = 0; mi < 4; ++mi) aFA[mi] = *(const bf16x8*)(aP[mi]);
#pragma unroll
  for (int ni = 0; ni < 2; ++ni) bFA[ni] = *(const bf16x8*)(bP[ni]);
#pragma unroll
  for (int mi = 0; mi < 4; ++mi) aFB[mi] = *(const bf16x8*)(aP[mi] + 32);
#pragma unroll
  for (int ni = 0; ni < 2; ++ni) bFB[ni] = *(const bf16x8*)(bP[ni] + 32);

  for (int k = 0; k < Kd; k += 64) {
    {
      const int kp = k + 64;
      bf16x8 aT[4], bT[2];
      if (kp < Kd) {
#pragma unroll
        for (int mi = 0; mi < 4; ++mi) aT[mi] = *(const bf16x8*)(aP[mi] + kp);
#pragma unroll
        for (int ni = 0; ni < 2; ++ni) bT[ni] = *(const bf16x8*)(bP[ni] + kp);
      }
#pragma unroll
      for (int ni = 0; ni < 2; ++ni)
#pragma unroll
        for (int mi = 0; mi < 4; ++mi)
          acc[mi][ni] = __builtin_amdgcn_mfma_f32_16x16x32_bf16(aFA[mi], bFA[ni], acc[mi][ni], 0, 0, 0);
      if (kp < Kd) {
#pragma unroll
        for (int mi = 0; mi < 4; ++mi) aFA[mi] = aT[mi];
#pragma unroll
        for (int ni = 0; ni < 2; ++ni) bFA[ni] = bT[ni];
      }
    }
    {
      const int kp = k + 96;
      bf16x8 aT[4], bT[2];
      if (kp < Kd) {
#pragma unroll
        for (int mi = 0; mi < 4; ++mi) aT[mi] = *(const bf16x8*)(aP[mi] + kp);
#pragma unroll
        for (int ni = 0; ni < 2; ++ni) bT[ni] = *(const bf16x8*)(bP[ni] + kp);
      }
#pragma unroll
      for (int ni = 0; ni < 2; ++ni)
#pragma unroll
        for (int mi = 0; mi < 4; ++mi)
          acc[mi][ni] = __builtin_amdgcn_mfma_f32_16x16x32_bf16(aFB[mi], bFB[ni], acc[mi][ni], 0, 0, 0);
      if (kp < Kd) {
#pragma unroll
        for (int mi = 0; mi < 4; ++mi) aFB[mi] = aT[mi];
#pragma unroll
        for (int ni = 0; ni < 2; ++ni) bFB[ni] = bT[ni];
      }
    }
  }

  float* dst = shd ? dsS : dsR;
#pragma unroll
  for (int mi = 0; mi < 4; ++mi)
#pragma unroll
    for (int r = 0; r < 4; ++r) {
      const int rowLoc = wm + 16 * mi + q * 4 + r;
      const int row = rowStart + rowLoc;
      if (row < rowEnd) {
#pragma unroll
        for (int ni = 0; ni < 2; ++ni)
          dst[(long)row * DMODEL + (n0 + wn + 16 * ni + l15)] = acc[mi][ni][r];
      }
    }
}

// ---------------- combine: out[t] = shared[t] + sum_k w * routed[slot_k] (round-9) ------
__global__ __launch_bounds__(256)
void combine_kernel(const float* __restrict__ dsR, const float* __restrict__ dsS,
                    const int* __restrict__ tokSlot, const float* __restrict__ tokW,
                    float* __restrict__ out) {
  const int t = blockIdx.x;
  const int j = threadIdx.x;  // float4 column
  float4 v = ((const float4*)(dsS + (long)t * DMODEL))[j];
#pragma unroll
  for (int k = 0; k < TOPK; ++k) {
    const int s = tokSlot[t * TOPK + k];
    const float w = tokW[t * TOPK + k];
    const float4 r = ((const float4*)(dsR + (long)s * DMODEL))[j];
    v.x += w * r.x; v.y += w * r.y; v.z += w * r.z; v.w += w * r.w;
  }
  ((float4*)(out + (long)t * DMODEL))[j] = v;
}

extern "C" void kernel_launch(void* const* d_in, const int* in_sizes, int n_in,
                              void* d_out, int out_size, void* d_ws, size_t ws_size,
                              hipStream_t stream) {
  const float* x  = (const float*)d_in[0];
  const float* gw = (const float*)d_in[2];
  const float* gb = (const float*)d_in[3];
  const float* gp = (const float*)d_in[4];
  const float* up = (const float*)d_in[5];
  const float* dp = (const float*)d_in[6];
  const float* sg = (const float*)d_in[7];
  const float* su = (const float*)d_in[8];
  const float* sd = (const float*)d_in[9];
  float* out = (float*)d_out;

  char* base = (char*)d_ws;
  size_t off = 0;
  auto alloc = [&](size_t bytes) -> char* {
    off = (off + 255) & ~(size_t)255;
    char* p = base + off;
    off += bytes;
    return p;
  };
  bf16* wbf = (bf16*)alloc((size_t)WTOT * 2);           // 56.6 MB bf16 weights
  bf16* xbf = (bf16*)alloc((size_t)TTOK * DMODEL * 2);
  bf16* interR = (bf16*)alloc((size_t)(TTOK * TOPK + 128) * INTER * 2);
  bf16* interS = (bf16*)alloc((size_t)TTOK * NSHI * 2);
  float* dsR = (float*)alloc((size_t)TTOK * TOPK * DMODEL * 4);
  float* dsS = (float*)alloc((size_t)TTOK * DMODEL * 4);
  float* scores = (float*)alloc((size_t)TTOK * NEXP * 4);
  float* tokW = (float*)alloc(TTOK * TOPK * 4);
  int* slotTok = (int*)alloc(TTOK * TOPK * 4);
  int* tokSlot = (int*)alloc(TTOK * TOPK * 4);
  int* offs = (int*)alloc((NEXP + 1) * 4);
  int* tileE = (int*)alloc(72 * 4);
  int* tileR = (int*)alloc(72 * 4);
  int* tileCnt = (int*)alloc(4);

  prep_kernel<<<SCORES_BLOCKS + CONV_BLOCKS, 256, 0, stream>>>(
      x, gw, scores, xbf, gp, up, dp, sg, su, sd, wbf);
  route_kernel<<<1, 1024, 0, stream>>>(scores, gb, tokW, slotTok, tokSlot,
                                       offs, tileE, tileR, tileCnt);

  gateup_gemm<<<dim3(16, 56, 1), 256, 0, stream>>>(
      xbf, slotTok, offs, tileE, tileR, tileCnt, wbf, interR, interS);
  down_gemm<<<dim3(16, 56, 1), 256, 0, stream>>>(
      interR, interS, offs, tileE, tileR, tileCnt, wbf, dsR, dsS);
  combine_kernel<<<TTOK, 256, 0, stream>>>(dsR, dsS, tokSlot, tokW, out);
}